// Round 3
// baseline (42.104 us; speedup 1.0000x reference)
//
#include <hip/hip_runtime.h>
#include <math.h>

#define FDIM 512
#define NL 1600
#define NR 64
#define NM (NL + NR)   // 1664 gathered rows (first 1600 -> A via W1top, last 64 -> Bm via W1bot)

typedef __attribute__((ext_vector_type(8))) short short8;      // 8 bf16 = 4 VGPR (MFMA A/B frag)
typedef __attribute__((ext_vector_type(4))) float f32x4;       // MFMA C/D frag
typedef __attribute__((ext_vector_type(8))) unsigned short ushort8;
typedef __attribute__((ext_vector_type(4))) unsigned short ushort4v;

__device__ __forceinline__ unsigned short f2bf(float f) {
    unsigned u = __float_as_uint(f);
    u += 0x7fffu + ((u >> 16) & 1u);   // RNE
    return (unsigned short)(u >> 16);
}

// K0: prep.
//  blocks 0..415  : gather+convert 4 rows each -> Abf[1664][512] bf16
//  blocks 416..927: transpose+convert W1 [1024][512] f32 -> WT[2][512][512] bf16, WT[h][n][k] = W1[h*512+k][n]
//  block  928     : wd[k] = W2[k][1] - W2[k][0]
__global__ __launch_bounds__(256) void k_prep(
    const float* __restrict__ SL, const float* __restrict__ SR,
    const float* __restrict__ W1, const float* __restrict__ W2,
    const int* __restrict__ idxL, const int* __restrict__ idxR,
    unsigned short* __restrict__ Abf, unsigned short* __restrict__ WT,
    float* __restrict__ wd)
{
    __shared__ float tile[32][33];
    const int t = threadIdx.x;
    if (blockIdx.x == 928) {
        float4 v = *(const float4*)(&W2[t * 4]);   // k = 2t, 2t+1
        wd[2 * t]     = v.y - v.x;
        wd[2 * t + 1] = v.w - v.z;
        return;
    }
    if (blockIdx.x < 416) {
        const int rowi = blockIdx.x * 4 + (t >> 6);
        const int k0 = (t & 63) * 8;
        long srow; const float* sp;
        if (rowi < NL) { srow = idxL[rowi];      sp = SL; }
        else           { srow = idxR[rowi - NL]; sp = SR; }
        const float* p = sp + srow * FDIM + k0;
        float4 v0 = *(const float4*)(p);
        float4 v1 = *(const float4*)(p + 4);
        ushort8 o;
        o[0]=f2bf(v0.x); o[1]=f2bf(v0.y); o[2]=f2bf(v0.z); o[3]=f2bf(v0.w);
        o[4]=f2bf(v1.x); o[5]=f2bf(v1.y); o[6]=f2bf(v1.z); o[7]=f2bf(v1.w);
        *(ushort8*)(Abf + (long)rowi * FDIM + k0) = o;
    } else {
        const int bidx = blockIdx.x - 416;
        const int ktile = bidx >> 4;   // 0..31 over fk (1024/32)
        const int ntile = bidx & 15;   // 0..15 over n  (512/32)
        {
            const int r  = t >> 3;         // 0..31 (fk offset)
            const int c4 = (t & 7) * 4;    // 0..28 (n offset)
            float4 v = *(const float4*)(&W1[(long)(ktile*32 + r) * FDIM + ntile*32 + c4]);
            tile[r][c4+0]=v.x; tile[r][c4+1]=v.y; tile[r][c4+2]=v.z; tile[r][c4+3]=v.w;
        }
        __syncthreads();
        const int h  = ktile >> 4;               // which half of W1 (top/bot)
        const int kb = (ktile & 15) * 32;        // k base within half
        const int nl = t >> 3;                   // 0..31
        const int k4 = (t & 7) * 4;
        ushort4v o;
        o[0]=f2bf(tile[k4+0][nl]); o[1]=f2bf(tile[k4+1][nl]);
        o[2]=f2bf(tile[k4+2][nl]); o[3]=f2bf(tile[k4+3][nl]);
        *(ushort4v*)(WT + (long)h*FDIM*FDIM + (long)(ntile*32 + nl)*FDIM + kb + k4) = o;
    }
}

// K1: bf16 MFMA GEMM, no LDS. 1 wave/block, wave tile 32(M) x 64(N), K=512.
// 4-deep register pipeline (prefetch distance 4 k-steps ~ 120cy of MFMA to hide L2 latency).
// A/B use the SAME slot->k mapping (row=lane&15, k=(lane>>4)*8+j); C/D: col=lane&15, row=(lane>>4)*4+r.
__global__ __launch_bounds__(64) void k_mfma(
    const short* __restrict__ Abf, const short* __restrict__ WT,
    const float* __restrict__ b1, float* __restrict__ A, float* __restrict__ Bm)
{
    const int bm = blockIdx.x;     // 0..51
    const int bn = blockIdx.y;     // 0..7
    const bool isB = bm >= 50;
    const int m0 = bm * 32, n0 = bn * 64;
    const short* wt = WT + (isB ? (long)FDIM * FDIM : 0);
    const int lane = threadIdx.x;
    const int row = lane & 15, g = lane >> 4;

    f32x4 acc[2][4] = {};
    const short* aP = Abf + (long)(m0 + row) * FDIM + g * 8;
    const short* bP = wt  + (long)(n0 + row) * FDIM + g * 8;

    short8 a[4][2], b[4][4];
    #pragma unroll
    for (int s = 0; s < 4; ++s) {
        #pragma unroll
        for (int i = 0; i < 2; i++) a[s][i] = *(const short8*)(aP + s * 32 + i * 16 * FDIM);
        #pragma unroll
        for (int j = 0; j < 4; j++) b[s][j] = *(const short8*)(bP + s * 32 + j * 16 * FDIM);
    }

    #pragma unroll
    for (int kk = 0; kk < 16; ++kk) {
        const int cur = kk & 3;                 // constant after full unroll
        #pragma unroll
        for (int i = 0; i < 2; i++)
            #pragma unroll
            for (int j = 0; j < 4; j++)
                acc[i][j] = __builtin_amdgcn_mfma_f32_16x16x32_bf16(a[cur][i], b[cur][j], acc[i][j], 0, 0, 0);
        if (kk < 12) {
            const int ko = (kk + 4) * 32;
            #pragma unroll
            for (int i = 0; i < 2; i++) a[cur][i] = *(const short8*)(aP + ko + i * 16 * FDIM);
            #pragma unroll
            for (int j = 0; j < 4; j++) b[cur][j] = *(const short8*)(bP + ko + j * 16 * FDIM);
        }
    }

    #pragma unroll
    for (int i = 0; i < 2; i++) {
        #pragma unroll
        for (int j = 0; j < 4; j++) {
            #pragma unroll
            for (int r = 0; r < 4; r++) {
                const int m = m0 + i * 16 + g * 4 + r;
                const int n = n0 + j * 16 + row;
                const float v = acc[i][j][r];
                if (isB) Bm[(long)(m - NL) * FDIM + n] = v + b1[n];
                else     A [(long)m * FDIM + n] = v;
            }
        }
    }
}

// K2: pairwise relu-dot + sigmoid.
// Wave <-> 2 l-rows, lane <-> r. A/wd: wave-uniform VMEM float4 loads (L2-hit).
// B: staged once per block into LDS with XOR permutation -> both stage-write and
// per-iter read are contiguous-1KB wave accesses = bank-conflict-free ds ops.
// out[l][r] = sigmoid( sum_k relu(A[l,k]+B[r,k]) * wd[k] + (b2[1]-b2[0]) )
__global__ __launch_bounds__(256) void k_pair(
    const float* __restrict__ A, const float* __restrict__ Bm,
    const float* __restrict__ wd, const float* __restrict__ b2,
    float* __restrict__ out)
{
    __shared__ float4 Bs[128 * 64];   // 128 KB: (r,k4) stored at Bs[k4*64 + (r ^ (k4&63))]
    const int t    = threadIdx.x;
    const int lane = t & 63;          // r
    const int w    = t >> 6;          // wave 0..3
    const int l0   = blockIdx.x * 8 + w * 2;

    const float4* Bm4 = (const float4*)Bm;
    #pragma unroll 8
    for (int i = 0; i < 32; ++i) {
        const int g = i * 256 + t;            // r = g>>7, k4 = g&127 (per-wave: r fixed, k4=lane-contig)
        float4 v = Bm4[g];
        const int r = g >> 7, k4 = g & 127;
        Bs[k4 * 64 + (r ^ (k4 & 63))] = v;
    }
    __syncthreads();

    const float4* A0 = (const float4*)(A + (long)l0 * FDIM);
    const float4* A1 = (const float4*)(A + (long)(l0 + 1) * FDIM);
    const float4* W4 = (const float4*)wd;
    float acc0 = 0.f, acc1 = 0.f;

    #pragma unroll 4
    for (int k4 = 0; k4 < 128; ++k4) {
        float4 b  = Bs[k4 * 64 + (lane ^ (k4 & 63))];
        float4 a0 = A0[k4];
        float4 a1 = A1[k4];
        float4 wv = W4[k4];
        acc0 = fmaf(fmaxf(a0.x + b.x, 0.f), wv.x, acc0);
        acc0 = fmaf(fmaxf(a0.y + b.y, 0.f), wv.y, acc0);
        acc0 = fmaf(fmaxf(a0.z + b.z, 0.f), wv.z, acc0);
        acc0 = fmaf(fmaxf(a0.w + b.w, 0.f), wv.w, acc0);
        acc1 = fmaf(fmaxf(a1.x + b.x, 0.f), wv.x, acc1);
        acc1 = fmaf(fmaxf(a1.y + b.y, 0.f), wv.y, acc1);
        acc1 = fmaf(fmaxf(a1.z + b.z, 0.f), wv.z, acc1);
        acc1 = fmaf(fmaxf(a1.w + b.w, 0.f), wv.w, acc1);
    }
    const float b2d = b2[1] - b2[0];
    out[(long)l0 * NR + lane]       = 1.f / (1.f + expf(-(acc0 + b2d)));
    out[(long)(l0 + 1) * NR + lane] = 1.f / (1.f + expf(-(acc1 + b2d)));
}

extern "C" void kernel_launch(void* const* d_in, const int* in_sizes, int n_in,
                              void* d_out, int out_size, void* d_ws, size_t ws_size,
                              hipStream_t stream) {
    const float* SL  = (const float*)d_in[0];   // [200000,512]
    const float* SR  = (const float*)d_in[1];   // [100000,512]
    const float* W1  = (const float*)d_in[2];   // [1024,512]
    const float* b1  = (const float*)d_in[3];   // [512]
    const float* W2  = (const float*)d_in[4];   // [512,2]
    const float* b2  = (const float*)d_in[5];   // [2]
    const int*   idxL = (const int*)d_in[6];    // [1600]
    const int*   idxR = (const int*)d_in[7];    // [64]
    float* out = (float*)d_out;                 // [1600,64]

    float* A  = (float*)d_ws;                          // [1600,512] f32
    float* Bm = A + (long)NL * FDIM;                   // [64,512]   f32
    float* wd = Bm + (long)NR * FDIM;                  // [512]      f32
    unsigned short* Abf = (unsigned short*)(wd + FDIM);        // [1664,512] bf16
    unsigned short* WT  = Abf + (long)NM * FDIM;               // [2,512,512] bf16

    k_prep<<<929, 256, 0, stream>>>(SL, SR, W1, W2, idxL, idxR, Abf, WT, wd);
    k_mfma<<<dim3(52, 8), 64, 0, stream>>>((const short*)Abf, (const short*)WT, b1, A, Bm);
    k_pair<<<NL / 8, 256, 0, stream>>>(A, Bm, wd, b2, out);
}

// Round 4
// 35.321 us; speedup vs baseline: 1.1921x; 1.1921x over previous
//
#include <hip/hip_runtime.h>
#include <math.h>

#define FDIM 512
#define NL 1600
#define NR 64
#define NM (NL + NR)   // 1664 gathered rows (first 1600 -> A via W1top, last 64 -> Bm via W1bot)

typedef __attribute__((ext_vector_type(8))) short short8;      // 8 bf16 = 4 VGPR (MFMA A/B frag)
typedef __attribute__((ext_vector_type(4))) float f32x4;       // MFMA C/D frag
typedef __attribute__((ext_vector_type(8))) unsigned short ushort8;
typedef __attribute__((ext_vector_type(4))) unsigned short ushort4v;

__device__ __forceinline__ unsigned short f2bf(float f) {
    unsigned u = __float_as_uint(f);
    u += 0x7fffu + ((u >> 16) & 1u);   // RNE
    return (unsigned short)(u >> 16);
}

// K0: prep.
//  blocks 0..415  : gather+convert 4 rows each -> Abf[1664][512] bf16
//  blocks 416..927: transpose+convert W1 -> WT[2][512][512] bf16, WT[h][n][k] = W1[h*512+k][n]
//  block  928     : wd[k] = W2[k][1] - W2[k][0]
__global__ __launch_bounds__(256) void k_prep(
    const float* __restrict__ SL, const float* __restrict__ SR,
    const float* __restrict__ W1, const float* __restrict__ W2,
    const int* __restrict__ idxL, const int* __restrict__ idxR,
    unsigned short* __restrict__ Abf, unsigned short* __restrict__ WT,
    float* __restrict__ wd)
{
    __shared__ float tile[32][33];
    const int t = threadIdx.x;
    if (blockIdx.x == 928) {
        float4 v = *(const float4*)(&W2[t * 4]);   // k = 2t, 2t+1
        wd[2 * t]     = v.y - v.x;
        wd[2 * t + 1] = v.w - v.z;
        return;
    }
    if (blockIdx.x < 416) {
        const int rowi = blockIdx.x * 4 + (t >> 6);
        const int k0 = (t & 63) * 8;
        long srow; const float* sp;
        if (rowi < NL) { srow = idxL[rowi];      sp = SL; }
        else           { srow = idxR[rowi - NL]; sp = SR; }
        const float* p = sp + srow * FDIM + k0;
        float4 v0 = *(const float4*)(p);
        float4 v1 = *(const float4*)(p + 4);
        ushort8 o;
        o[0]=f2bf(v0.x); o[1]=f2bf(v0.y); o[2]=f2bf(v0.z); o[3]=f2bf(v0.w);
        o[4]=f2bf(v1.x); o[5]=f2bf(v1.y); o[6]=f2bf(v1.z); o[7]=f2bf(v1.w);
        *(ushort8*)(Abf + (long)rowi * FDIM + k0) = o;
    } else {
        const int bidx = blockIdx.x - 416;
        const int ktile = bidx >> 4;   // 0..31 over fk (1024/32)
        const int ntile = bidx & 15;   // 0..15 over n  (512/32)
        {
            const int r  = t >> 3;         // 0..31 (fk offset)
            const int c4 = (t & 7) * 4;    // 0..28 (n offset)
            float4 v = *(const float4*)(&W1[(long)(ktile*32 + r) * FDIM + ntile*32 + c4]);
            tile[r][c4+0]=v.x; tile[r][c4+1]=v.y; tile[r][c4+2]=v.z; tile[r][c4+3]=v.w;
        }
        __syncthreads();
        const int h  = ktile >> 4;               // which half of W1 (top/bot)
        const int kb = (ktile & 15) * 32;        // k base within half
        const int nl = t >> 3;                   // 0..31
        const int k4 = (t & 7) * 4;
        ushort4v o;
        o[0]=f2bf(tile[k4+0][nl]); o[1]=f2bf(tile[k4+1][nl]);
        o[2]=f2bf(tile[k4+2][nl]); o[3]=f2bf(tile[k4+3][nl]);
        *(ushort4v*)(WT + (long)h*FDIM*FDIM + (long)(ntile*32 + nl)*FDIM + kb + k4) = o;
    }
}

// K1: bf16 MFMA GEMM, no LDS. 1 wave/block, wave tile 32(M) x 64(N), K=512.
// 6-deep register pipeline: 36 loads in flight, steady-state L2 latency fully
// covered by 5 x 16-MFMA clusters (~400 cyc) between issue and consume.
// A/B use the SAME slot->k mapping (row=lane&15, k=(lane>>4)*8+j); C/D: col=lane&15, row=(lane>>4)*4+r.
__global__ __launch_bounds__(64) void k_mfma(
    const short* __restrict__ Abf, const short* __restrict__ WT,
    const float* __restrict__ b1, float* __restrict__ A, float* __restrict__ Bm)
{
    const int bm = blockIdx.x;     // 0..51
    const int bn = blockIdx.y;     // 0..7
    const bool isB = bm >= 50;
    const int m0 = bm * 32, n0 = bn * 64;
    const short* wt = WT + (isB ? (long)FDIM * FDIM : 0);
    const int lane = threadIdx.x;
    const int row = lane & 15, g = lane >> 4;

    f32x4 acc[2][4] = {};
    const short* aP = Abf + (long)(m0 + row) * FDIM + g * 8;
    const short* bP = wt  + (long)(n0 + row) * FDIM + g * 8;

    short8 a[6][2], b[6][4];
    #pragma unroll
    for (int s = 0; s < 6; ++s) {
        #pragma unroll
        for (int i = 0; i < 2; i++) a[s][i] = *(const short8*)(aP + s * 32 + i * 16 * FDIM);
        #pragma unroll
        for (int j = 0; j < 4; j++) b[s][j] = *(const short8*)(bP + s * 32 + j * 16 * FDIM);
    }

    #pragma unroll
    for (int kk = 0; kk < 16; ++kk) {
        const int cur = kk % 6;                 // compile-time after full unroll
        #pragma unroll
        for (int i = 0; i < 2; i++)
            #pragma unroll
            for (int j = 0; j < 4; j++)
                acc[i][j] = __builtin_amdgcn_mfma_f32_16x16x32_bf16(a[cur][i], b[cur][j], acc[i][j], 0, 0, 0);
        if (kk < 10) {
            const int ko = (kk + 6) * 32;
            #pragma unroll
            for (int i = 0; i < 2; i++) a[cur][i] = *(const short8*)(aP + ko + i * 16 * FDIM);
            #pragma unroll
            for (int j = 0; j < 4; j++) b[cur][j] = *(const short8*)(bP + ko + j * 16 * FDIM);
        }
    }

    #pragma unroll
    for (int i = 0; i < 2; i++) {
        #pragma unroll
        for (int j = 0; j < 4; j++) {
            #pragma unroll
            for (int r = 0; r < 4; r++) {
                const int m = m0 + i * 16 + g * 4 + r;
                const int n = n0 + j * 16 + row;
                const float v = acc[i][j][r];
                if (isB) Bm[(long)(m - NL) * FDIM + n] = v + b1[n];
                else     A [(long)m * FDIM + n] = v;
            }
        }
    }
}

// K2: pairwise relu-dot, k-split x8 for occupancy (3200 waves = 3.1/SIMD).
// Block = (l-tile of 16, k-chunk of 64). LDS = 16KB chunk [16 k4][64 r] float4,
// XOR r^k4 layout -> staging writes cheap, per-iter reads contiguous-1KB (BW-optimal).
// Wave = 4 l rows (independent accumulators for ILP), lane = r.
// Part[kq][l][r] = sum_{k in chunk} relu(A[l,k]+B[r,k]) * wd[k]
__global__ __launch_bounds__(256) void k_pair(
    const float* __restrict__ A, const float* __restrict__ Bm,
    const float* __restrict__ wd, float* __restrict__ Part)
{
    __shared__ float4 Bs[16 * 64];   // 16 KB
    const int t    = threadIdx.x;
    const int lane = t & 63;
    const int w    = t >> 6;          // wave 0..3
    const int lt   = blockIdx.x;      // 0..99
    const int kq   = blockIdx.y;      // 0..7

    const float4* Bm4 = (const float4*)Bm;
    #pragma unroll
    for (int i = 0; i < 4; ++i) {
        const int idx = i * 256 + t;          // 0..1023
        const int r = idx >> 4, c = idx & 15;
        Bs[c * 64 + (r ^ c)] = Bm4[r * 128 + kq * 16 + c];
    }
    __syncthreads();

    const int lb = lt * 16 + w * 4;
    const float4* A0 = (const float4*)(A + (long)(lb + 0) * FDIM) + kq * 16;
    const float4* A1 = (const float4*)(A + (long)(lb + 1) * FDIM) + kq * 16;
    const float4* A2 = (const float4*)(A + (long)(lb + 2) * FDIM) + kq * 16;
    const float4* A3 = (const float4*)(A + (long)(lb + 3) * FDIM) + kq * 16;
    const float4* W4 = (const float4*)wd + kq * 16;

    float acc0 = 0.f, acc1 = 0.f, acc2 = 0.f, acc3 = 0.f;
    #pragma unroll
    for (int c = 0; c < 16; ++c) {
        float4 b  = Bs[c * 64 + (lane ^ c)];
        float4 wv = W4[c];
        float4 a0 = A0[c], a1 = A1[c], a2 = A2[c], a3 = A3[c];
        acc0 = fmaf(fmaxf(a0.x + b.x, 0.f), wv.x, acc0);
        acc0 = fmaf(fmaxf(a0.y + b.y, 0.f), wv.y, acc0);
        acc0 = fmaf(fmaxf(a0.z + b.z, 0.f), wv.z, acc0);
        acc0 = fmaf(fmaxf(a0.w + b.w, 0.f), wv.w, acc0);
        acc1 = fmaf(fmaxf(a1.x + b.x, 0.f), wv.x, acc1);
        acc1 = fmaf(fmaxf(a1.y + b.y, 0.f), wv.y, acc1);
        acc1 = fmaf(fmaxf(a1.z + b.z, 0.f), wv.z, acc1);
        acc1 = fmaf(fmaxf(a1.w + b.w, 0.f), wv.w, acc1);
        acc2 = fmaf(fmaxf(a2.x + b.x, 0.f), wv.x, acc2);
        acc2 = fmaf(fmaxf(a2.y + b.y, 0.f), wv.y, acc2);
        acc2 = fmaf(fmaxf(a2.z + b.z, 0.f), wv.z, acc2);
        acc2 = fmaf(fmaxf(a2.w + b.w, 0.f), wv.w, acc2);
        acc3 = fmaf(fmaxf(a3.x + b.x, 0.f), wv.x, acc3);
        acc3 = fmaf(fmaxf(a3.y + b.y, 0.f), wv.y, acc3);
        acc3 = fmaf(fmaxf(a3.z + b.z, 0.f), wv.z, acc3);
        acc3 = fmaf(fmaxf(a3.w + b.w, 0.f), wv.w, acc3);
    }
    float* P = Part + ((long)kq * NL + lb) * NR + lane;
    P[0 * NR] = acc0;
    P[1 * NR] = acc1;
    P[2 * NR] = acc2;
    P[3 * NR] = acc3;
}

// K3: sum the 8 k-chunk partials + sigmoid.
__global__ __launch_bounds__(256) void k_final(
    const float* __restrict__ Part, const float* __restrict__ b2,
    float* __restrict__ out)
{
    const int gid = blockIdx.x * 256 + threadIdx.x;   // 0..102399
    float s = b2[1] - b2[0];
    #pragma unroll
    for (int q = 0; q < 8; ++q) s += Part[(long)q * NL * NR + gid];
    out[gid] = 1.f / (1.f + expf(-s));
}

extern "C" void kernel_launch(void* const* d_in, const int* in_sizes, int n_in,
                              void* d_out, int out_size, void* d_ws, size_t ws_size,
                              hipStream_t stream) {
    const float* SL  = (const float*)d_in[0];   // [200000,512]
    const float* SR  = (const float*)d_in[1];   // [100000,512]
    const float* W1  = (const float*)d_in[2];   // [1024,512]
    const float* b1  = (const float*)d_in[3];   // [512]
    const float* W2  = (const float*)d_in[4];   // [512,2]
    const float* b2  = (const float*)d_in[5];   // [2]
    const int*   idxL = (const int*)d_in[6];    // [1600]
    const int*   idxR = (const int*)d_in[7];    // [64]
    float* out = (float*)d_out;                 // [1600,64]

    float* A    = (float*)d_ws;                        // [1600,512] f32
    float* Bm   = A + (long)NL * FDIM;                 // [64,512]   f32
    float* wd   = Bm + (long)NR * FDIM;                // [512]      f32
    float* Part = wd + FDIM;                           // [8,1600,64] f32
    unsigned short* Abf = (unsigned short*)(Part + (long)8 * NL * NR);  // [1664,512] bf16
    unsigned short* WT  = Abf + (long)NM * FDIM;                        // [2,512,512] bf16

    k_prep<<<929, 256, 0, stream>>>(SL, SR, W1, W2, idxL, idxR, Abf, WT, wd);
    k_mfma<<<dim3(52, 8), 64, 0, stream>>>((const short*)Abf, (const short*)WT, b1, A, Bm);
    k_pair<<<dim3(100, 8), 256, 0, stream>>>(A, Bm, wd, Part);
    k_final<<<(NL * NR) / 256, 256, 0, stream>>>(Part, b2, out);
}